// Round 1
// 391.874 us; speedup vs baseline: 1.0664x; 1.0664x over previous
//
#include <hip/hip_runtime.h>
#include <cstdint>
#include <cstddef>

// Problem constants
#define L_   256
#define Q_   21
#define M_   8192
#define QQ   441
#define JCH  16            // j-blocks staged per barrier in k_main
#define SCALE    32.0f     // J scaled by 32 before fp16 quantization
#define INVSCALE 0.03125f
#define NPAIR ((L_ * (L_ - 1)) / 2)   // 32640 valid (i,j) pairs

// Jt block layout (per (i,j)): 21 rows (k = symbol), each row 48 B =
// 21 fp16(J*32) elems a=0..20 + 3 zero pad halves. Row stride 12 dwords.
// Block = 21*48 B padded to 1024 B (256 dwords). Jt = 64 MiB.
//
// ws layout (floats at base):
//   acc[0]=wsum  acc[2]=h2_sum
//   acc[4..259]   = 256 J2 partial slots
//   acc[260..387] = 128 ll partial slots
//   [2048 .. +2MiB)  seqsP: dword[jq*M + b] = symbols j=4jq..4jq+3 (bytes)
//   [2048+2MiB ..)   Jt (fp16 blocks)

typedef _Float16 h2 __attribute__((ext_vector_type(2)));

__device__ __forceinline__ float block_reduce_sum(float v) {
    __shared__ float s[256];
    int t = threadIdx.x;
    __syncthreads();           // guard against reuse hazard
    s[t] = v;
    __syncthreads();
#pragma unroll
    for (int o = 128; o > 0; o >>= 1) {
        if (t < o) s[t] += s[t + o];
        __syncthreads();
    }
    return s[0];
}

// ---- prep A: J fp32 -> Jt fp16 transpose + reg_J ----
// Grid (16, 255): block (s, iy) handles row i = iy+1, pairs j = 16s .. 16s+15.
// For fixed i the J blocks j=0..i-1 are CONTIGUOUS (i*441 f32) and the Jt
// output blocks are CONTIGUOUS (i KiB); segment bases are 16-B aligned
// (441*16s and 441*256*i are both multiples of 4 dwords). So: float4
// coalesced loads in, uint4 coalesced writes out, transpose via LDS.
__global__ __launch_bounds__(256) void k_prep(const float* __restrict__ J,
                                              unsigned* __restrict__ Jt,
                                              float* __restrict__ acc) {
    __shared__ __align__(16) float sB[16 * QQ];   // 28224 B
    const int t  = threadIdx.x;
    const int i  = blockIdx.y + 1;
    const int j0 = blockIdx.x << 4;
    if (j0 >= i) return;                          // uniform across block
    const int jn = min(16, i - j0);

    const size_t base_dw = (size_t)(i * L_ + j0) * QQ;
    const float* src = J + base_dw;
    const int ndw = jn * QQ;
    const int nf4 = ndw >> 2;
    const int rem = ndw & 3;                      // 441 % 4 == 1 -> rem = jn % 4

    // phase 1: contiguous float4 load -> LDS, accumulate sum(J^2)
    float v2 = 0.f;
    {
        const float4* src4 = reinterpret_cast<const float4*>(src);
        float4* s4 = reinterpret_cast<float4*>(sB);
        for (int q = t; q < nf4; q += 256) {
            float4 v = src4[q];
            s4[q] = v;
            v2 += v.x * v.x + v.y * v.y + v.z * v.z + v.w * v.w;
        }
        if (t < rem) {
            float v = src[(nf4 << 2) + t];
            sB[(nf4 << 2) + t] = v;
            v2 += v * v;
        }
    }
    __syncthreads();

    // phase 2: transpose-pack. uint4 g covers output dwords 4g..4g+3;
    // pair p = g>>6 (so each wave reads from ONE pair's LDS region).
    // Output dword dd (0..255): kr = dd/12 (symbol row), halves a0=2*(dd%12).
    {
        const int nu4 = jn << 6;
        uint4* dst = reinterpret_cast<uint4*>(Jt + (size_t)(i * L_ + j0) * 256);
        for (int g = t; g < nu4; g += 256) {
            const float* s = sB + (g >> 6) * QQ;
            unsigned wv[4];
#pragma unroll
            for (int c = 0; c < 4; ++c) {
                const int dd = ((g & 63) << 2) | c;   // 0..255
                const int kr = dd / 12;
                const int dw = dd - 12 * kr;
                const int a0 = dw << 1;
                unsigned outw = 0;
                if (kr < Q_) {
                    float x0 = (a0     < Q_) ? s[(a0    ) * Q_ + kr] : 0.f;
                    float x1 = (a0 + 1 < Q_) ? s[(a0 + 1) * Q_ + kr] : 0.f;
                    union { _Float16 hh[2]; unsigned u; } uu;
                    uu.hh[0] = (_Float16)(x0 * SCALE);
                    uu.hh[1] = (_Float16)(x1 * SCALE);
                    outw = uu.u;
                }
                wv[c] = outw;
            }
            uint4 o; o.x = wv[0]; o.y = wv[1]; o.z = wv[2]; o.w = wv[3];
            dst[g] = o;
        }
    }

    float r = block_reduce_sum(v2);
    if (t == 0) atomicAdd(&acc[4 + ((blockIdx.y * 16 + blockIdx.x) & 255)], r);
}

// ---- prep B: pack seqs + wsum + h2 (258 blocks: whole chip participates) ----
__global__ __launch_bounds__(256) void k_prep2(const int* __restrict__ seqs,
                                               const float* __restrict__ w,
                                               const float* __restrict__ h,
                                               unsigned* __restrict__ seqsP,
                                               float* __restrict__ acc) {
    const int bid = blockIdx.x;
    const int t = threadIdx.x;
    if (bid < 256) {
        const int bc = bid >> 3;          // b-chunk 0..31
        const int jc = bid & 7;           // jq-chunk 0..7
        const int b = bc * 256 + t;
        const int4* row = reinterpret_cast<const int4*>(seqs + (size_t)b * L_);
#pragma unroll
        for (int u = 0; u < 8; ++u) {
            const int jq = jc * 8 + u;
            int4 v = row[jq];
            unsigned p = (unsigned)(v.x & 255) | ((unsigned)(v.y & 255) << 8) |
                         ((unsigned)(v.z & 255) << 16) | ((unsigned)(v.w & 255) << 24);
            seqsP[jq * M_ + b] = p;
        }
    } else if (bid == 256) {
        float v = 0.f;
        for (int x = t; x < M_; x += 256) v += w[x];
        float r = block_reduce_sum(v);
        if (t == 0) acc[0] = r;
    } else {
        float v2 = 0.f;
        for (int x = t; x < L_ * Q_; x += 256) { float y = h[x]; v2 += y * y; }
        float r2 = block_reduce_sum(v2);
        if (t == 0) acc[2] = r2;
    }
}

// Inner body: row k of staged block jj, 12 packed fp16 adds (24 halves incl pad).
#define BODY(jj)                                                                    \
    {                                                                               \
        const unsigned kk = (idxw[(jj) >> 2] >> (((jj) & 3) * 8)) & 255u;           \
        const uint4* rp = reinterpret_cast<const uint4*>(sJ) + ((jj) * 64 + kk * 3);\
        union { uint4 u; h2 h[4]; } ra, rb, rc;                                     \
        ra.u = rp[0]; rb.u = rp[1]; rc.u = rp[2];                                   \
        acch[0]  += ra.h[0]; acch[1]  += ra.h[1];                                   \
        acch[2]  += ra.h[2]; acch[3]  += ra.h[3];                                   \
        acch[4]  += rb.h[0]; acch[5]  += rb.h[1];                                   \
        acch[6]  += rb.h[2]; acch[7]  += rb.h[3];                                   \
        acch[8]  += rc.h[0]; acch[9]  += rc.h[1];                                   \
        acch[10] += rc.h[2]; acch[11] += rc.h[3];                                   \
    }

// ---- main: LDS-staged fp16 gather, packed-fp16 accumulate (unchanged) ----
__global__ __launch_bounds__(256, 8) void k_main(const unsigned* __restrict__ Jt,
                                                 const float* __restrict__ h,
                                                 const unsigned* __restrict__ seqsP,
                                                 const float* __restrict__ weights,
                                                 float* __restrict__ acc) {
    __shared__ unsigned sJ[JCH * 256];   // 16 KiB: JCH blocks x 256 dwords

    const int bid = blockIdx.x;
    const int i = (L_ - 1) - (bid >> 5);              // heavy blocks first
    const int b = ((bid & 31) << 8) + threadIdx.x;    // [0, 8192)

    // packed fp16 accumulators (scaled by SCALE); elems 21..23 stay ~0 (pads)
    h2 acch[12];
    const float* hp = h + i * Q_;
#pragma unroll
    for (int m = 0; m < 10; ++m) {
        acch[m].x = (_Float16)(hp[2 * m] * SCALE);
        acch[m].y = (_Float16)(hp[2 * m + 1] * SCALE);
    }
    acch[10].x = (_Float16)(hp[20] * SCALE); acch[10].y = (_Float16)0.f;
    acch[11].x = (_Float16)0.f;              acch[11].y = (_Float16)0.f;

    const unsigned* Jrow = Jt + (size_t)i * (256 * 256);  // dwords of row i

    const int nStages = i >> 4;   // full 16-j stages
    const int rem     = i & 15;

    for (int s = 0; s < nStages; ++s) {
        const int j0 = s << 4;
        {
            const uint4* src = reinterpret_cast<const uint4*>(Jrow + j0 * 256);
            uint4* dst = reinterpret_cast<uint4*>(sJ);
#pragma unroll
            for (int n = 0; n < 4; ++n) {
                dst[n * 256 + threadIdx.x] = src[n * 256 + threadIdx.x];
            }
        }
        __syncthreads();

        unsigned idxw[JCH / 4];
#pragma unroll
        for (int q = 0; q < JCH / 4; ++q) {
            idxw[q] = seqsP[((j0 >> 2) + q) * M_ + b];
        }

#pragma unroll
        for (int jj = 0; jj < JCH; ++jj) BODY(jj);

        __syncthreads();
    }

    if (rem) {
        const int j0 = nStages << 4;   // <= 240; staging j0..j0+15 in-bounds
        {
            const uint4* src = reinterpret_cast<const uint4*>(Jrow + j0 * 256);
            uint4* dst = reinterpret_cast<uint4*>(sJ);
#pragma unroll
            for (int n = 0; n < 4; ++n) {
                dst[n * 256 + threadIdx.x] = src[n * 256 + threadIdx.x];
            }
        }
        __syncthreads();

        unsigned idxw[JCH / 4];
#pragma unroll
        for (int q = 0; q < JCH / 4; ++q) {
            idxw[q] = seqsP[((j0 >> 2) + q) * M_ + b];
        }

#pragma unroll
        for (int jj = 0; jj < JCH; ++jj) {
            if (jj >= rem) break;
            BODY(jj);
        }
    }

    // unpack logits to fp32
    float l[21];
#pragma unroll
    for (int m = 0; m < 10; ++m) {
        l[2 * m]     = (float)acch[m].x * INVSCALE;
        l[2 * m + 1] = (float)acch[m].y * INVSCALE;
    }
    l[20] = (float)acch[10].x * INVSCALE;

    // label gather from packed seqs
    unsigned lw = seqsP[(i >> 2) * M_ + b];
    int lbl = (int)((lw >> ((i & 3) * 8)) & 255u);

    float m = l[0];
#pragma unroll
    for (int a = 1; a < 21; ++a) m = fmaxf(m, l[a]);
    float s = 0.f;
    float lv = l[0];
#pragma unroll
    for (int a = 0; a < 21; ++a) {
        s += __expf(l[a] - m);
        if (a > 0) lv = (a == lbl) ? l[a] : lv;
    }
    float ll = (lv - m) - __logf(s);
    float contrib = weights[b] * ll;

    float r = block_reduce_sum(contrib);
    if (threadIdx.x == 0) atomicAdd(&acc[260 + (bid & 127)], r);
}

// ---- finalize: reduce partial slots + compose outputs ----
__global__ void k_final(const float* __restrict__ acc, float* __restrict__ out) {
    int t = threadIdx.x;
    float j2p = acc[4 + t];                       // 256 J2 slots
    float j2 = block_reduce_sum(j2p);
    float llp = (t < 128) ? acc[260 + t] : 0.f;   // 128 ll slots
    float lls = block_reduce_sum(llp);
    if (t == 0) {
        float wsum = fmaxf(acc[0], 1e-12f);
        float nll = -lls / wsum;
        float reg = 0.5e-6f * acc[2] + 0.5e-4f * j2;
        out[0] = nll + reg;
        out[1] = nll;
        out[2] = reg;
    }
}

extern "C" void kernel_launch(void* const* d_in, const int* in_sizes, int n_in,
                              void* d_out, int out_size, void* d_ws, size_t ws_size,
                              hipStream_t stream) {
    const int*   seqs    = (const int*)d_in[0];
    const float* weights = (const float*)d_in[1];
    const float* h       = (const float*)d_in[2];
    const float* J       = (const float*)d_in[3];
    float* out = (float*)d_out;

    char* ws = (char*)d_ws;
    float*    acc   = (float*)ws;
    unsigned* seqsP = (unsigned*)(ws + 2048);
    unsigned* Jt    = (unsigned*)(ws + 2048 + (size_t)(L_ / 4) * M_ * sizeof(unsigned));

    hipMemsetAsync(d_ws, 0, 2048, stream);

    dim3 pg(16, 255);
    k_prep<<<pg, 256, 0, stream>>>(J, Jt, acc);
    k_prep2<<<258, 256, 0, stream>>>(seqs, weights, h, seqsP, acc);
    k_main<<<L_ * (M_ / 256), 256, 0, stream>>>(Jt, h, seqsP, weights, acc);
    k_final<<<1, 256, 0, stream>>>(acc, out);
}